// Round 10
// baseline (1193.245 us; speedup 1.0000x reference)
//
#include <hip/hip_runtime.h>
#include <math.h>

#define NEGBIG (-1e30f)

typedef __bf16 bf16x8 __attribute__((ext_vector_type(8)));
typedef float  f32x4  __attribute__((ext_vector_type(4)));

// Sizes: B=512, S=8, U=512, D=32, G=8, DIM_IN=4096, DAG=2048
// out layout: att[512*16384] | ga[512*2048] | w[512^3] | outputs[512*16384]
// No-max softmax: scores kernel stores p = exp(s) (masked -> 0) into the w
// region and accumulates L_g; stats cell (b,u) floats [0..7] = 1/(8 L_g).
// emit kernel: w = p * IL_g + PV accumulation; overwrites stats cells.

// ---------------- K1/K2: per-split fp32 GEMM (64x64 tile, Kstep 16) ----------------
__global__ __launch_bounds__(256) void gemm_split(
    const float* __restrict__ A, int lda, int Ksz,
    const float* __restrict__ Bw, int NS,
    const float* __restrict__ bias,
    float* __restrict__ C, int ldc)
{
  const int n0 = blockIdx.x * 64;
  const int b0 = blockIdx.y * 64;
  const int s  = n0 / NS;
  const float* Bp = Bw + (size_t)s * Ksz * NS;
  const int nloc0 = n0 - s * NS;
  const int acol0 = s * Ksz;

  __shared__ float As[16][64];
  __shared__ float Bs[16][64];

  const int t  = threadIdx.x;
  const int tb = t & 15, tn = t >> 4;
  float acc[4][4] = {};

  for (int k0 = 0; k0 < Ksz; k0 += 16) {
    {
      int r = t & 63, g = t >> 6;
      float4 v = *reinterpret_cast<const float4*>(
          A + (size_t)(b0 + r) * lda + acol0 + k0 + 4 * g);
      As[4*g+0][r] = v.x; As[4*g+1][r] = v.y; As[4*g+2][r] = v.z; As[4*g+3][r] = v.w;
    }
    {
      int kk = t >> 4, n4 = t & 15;
      float4 v = *reinterpret_cast<const float4*>(
          Bp + (size_t)(k0 + kk) * NS + nloc0 + 4 * n4);
      *reinterpret_cast<float4*>(&Bs[kk][4*n4]) = v;
    }
    __syncthreads();
#pragma unroll
    for (int k = 0; k < 16; ++k) {
      float4 a4 = *reinterpret_cast<const float4*>(&As[k][4*tb]);
      float4 b4 = *reinterpret_cast<const float4*>(&Bs[k][4*tn]);
      float av[4] = {a4.x, a4.y, a4.z, a4.w};
      float bv[4] = {b4.x, b4.y, b4.z, b4.w};
#pragma unroll
      for (int i = 0; i < 4; ++i)
#pragma unroll
        for (int j = 0; j < 4; ++j)
          acc[i][j] = fmaf(av[i], bv[j], acc[i][j]);
    }
    __syncthreads();
  }
#pragma unroll
  for (int i = 0; i < 4; ++i) {
    int row = b0 + 4*tb + i;
    int col = n0 + 4*tn;
    float4 o;
    o.x = acc[i][0] + bias[col + 0];
    o.y = acc[i][1] + bias[col + 1];
    o.z = acc[i][2] + bias[col + 2];
    o.w = acc[i][3] + bias[col + 3];
    *reinterpret_cast<float4*>(C + (size_t)row * ldc + col) = o;
  }
}

// ---------------- K3a (MFMA v3): p = exp(masked score) + group sums ----------------
// Block 16b x 16u; 16-m chunks. ma REGISTER-double-buffered (issue-early /
// ds_write-late): per chunk {ds_write staged(c); barrier B; issue loads(c+1)
// + rnd(c); MFMA phase; barrier C; emit(c)}. Every load has >= one full
// compute phase of latency cover before any barrier drain.
// MaL f4-slot s = (m<<7)+(u<<3)+(d4 ^ (m&7)) (source-side swizzle; B-frag
// reads 2-way). Wave w owns u-locals 4w..4w+3; A-frags (att) split hi/lo bf16
// in regs once; 3 MFMAs per u (hi*lo + lo*hi + hi*hi); C -> tr[(b*16+m)*17+u].
// Emit: thread (bl,ml) owns (b, m=16c+ml) for 16 u: coalesced rnd f4, p =
// exp(s*tmp) (masked -> 0), coalesced 64 B w-writes, Ls[16] regs (g=ml&7
// static). shfl_xor(8) merges partners; ml<8 writes IL = 1/(8L).
__global__ __launch_bounds__(256) void scores_mfma_v3(
    const float* __restrict__ att,   // [512][512][32]
    const float* __restrict__ ma,    // [512][512][32]
    const float* __restrict__ rnd,   // [512][512][512]
    const float* __restrict__ temp,  // [512]
    float* __restrict__ wout,        // [512][512][512] <- p values
    float* __restrict__ stats)       // outs region base
{
  __shared__ float MaL[2048 * 4];    // 32 KB: staged ma chunk (f4 slots)
  __shared__ float tr[256 * 17];     // 17 KB: C transpose
  const int b0 = blockIdx.x * 16;
  const int u0 = blockIdx.y * 16;
  const int t  = threadIdx.x;
  const int w  = t >> 6, l = t & 63;
  const int lm = l & 15, kb = l >> 4;      // MFMA lane decode
  const int bl = t >> 4, ml = t & 15;      // emit decode
  const int gb = b0 + bl;

  // temperatures (emit role)
  float tvf[16];
#pragma unroll
  for (int q = 0; q < 4; ++q) {
    float4 tq = *reinterpret_cast<const float4*>(temp + u0 + 4 * q);
    tvf[4*q+0] = tq.x; tvf[4*q+1] = tq.y; tvf[4*q+2] = tq.z; tvf[4*q+3] = tq.w;
  }

  // A-fragments for this wave's 4 u's, split hi/lo bf16 (loaded once)
  bf16x8 Ahi[4], Alo[4];
#pragma unroll
  for (int q = 0; q < 4; ++q) {
    const float* ap = att + (size_t)(b0 + lm) * 16384
                    + (size_t)(u0 + 4 * w + q) * 32 + kb * 8;
    float4 a0 = *reinterpret_cast<const float4*>(ap);
    float4 a1 = *reinterpret_cast<const float4*>(ap + 4);
    float af[8] = {a0.x, a0.y, a0.z, a0.w, a1.x, a1.y, a1.z, a1.w};
#pragma unroll
    for (int j = 0; j < 8; ++j) {
      __bf16 h = (__bf16)af[j];
      Ahi[q][j] = h;
      Alo[q][j] = (__bf16)(af[j] - (float)h);
    }
  }

  // staging source offsets: slot s = k*256 + t holds ma(m=s>>7, u=(s>>3)&15,
  // d4 = (s&7) ^ (m&7)) of the current chunk
  int off[8];
#pragma unroll
  for (int k = 0; k < 8; ++k) {
    int s = k * 256 + t;
    int mm = s >> 7, uu = (s >> 3) & 15, d4s = s & 7;
    off[k] = mm * 16384 + (u0 + uu) * 32 + ((d4s ^ (mm & 7)) << 2);
  }

  float Ls[16];
#pragma unroll
  for (int u = 0; u < 16; ++u) Ls[u] = 0.f;

  const float* rb = rnd  + (size_t)gb * 262144 + u0;
  float*       wb = wout + (size_t)gb * 262144 + u0;

  // prologue: chunk 0 staged into regs
  float4 Sg[8];
#pragma unroll
  for (int k = 0; k < 8; ++k)
    Sg[k] = *reinterpret_cast<const float4*>(ma + (size_t)off[k]);

#pragma unroll 1
  for (int c = 0; c < 32; ++c) {
    const int m0 = c * 16;

    // ---- publish chunk c to LDS (readers of c-1 finished before barrier C) ----
#pragma unroll
    for (int k = 0; k < 8; ++k)
      *reinterpret_cast<float4*>(&MaL[(k * 256 + t) * 4]) = Sg[k];
    __syncthreads();                 // B: MaL(c) visible; tr(c-1) readers done

    // ---- issue chunk c+1 staging + this chunk's rnd (cover = MFMA phase+) ----
    if (c < 31) {
#pragma unroll
      for (int k = 0; k < 8; ++k)
        Sg[k] = *reinterpret_cast<const float4*>(
            ma + (size_t)off[k] + (size_t)(m0 + 16) * 16384);
    }
    float4 rv[4];
#pragma unroll
    for (int q = 0; q < 4; ++q)
      rv[q] = *reinterpret_cast<const float4*>(rb + (size_t)(m0 + ml) * 512 + 4 * q);

    // ---- MFMA role: 4 u's of this wave ----
#pragma unroll
    for (int q = 0; q < 4; ++q) {
      const int uq = 4 * w + q;
      const int s0 = (lm << 7) + (uq << 3) + ((2 * kb)     ^ (lm & 7));
      const int s1 = (lm << 7) + (uq << 3) + ((2 * kb + 1) ^ (lm & 7));
      float4 g0 = *reinterpret_cast<const float4*>(&MaL[s0 * 4]);
      float4 g1 = *reinterpret_cast<const float4*>(&MaL[s1 * 4]);
      float bf[8] = {g0.x, g0.y, g0.z, g0.w, g1.x, g1.y, g1.z, g1.w};
      bf16x8 Bhi, Blo;
#pragma unroll
      for (int j = 0; j < 8; ++j) {
        __bf16 h = (__bf16)bf[j];
        Bhi[j] = h;
        Blo[j] = (__bf16)(bf[j] - (float)h);
      }
      f32x4 acc = {0.f, 0.f, 0.f, 0.f};
      acc = __builtin_amdgcn_mfma_f32_16x16x32_bf16(Ahi[q], Blo, acc, 0, 0, 0);
      acc = __builtin_amdgcn_mfma_f32_16x16x32_bf16(Alo[q], Bhi, acc, 0, 0, 0);
      acc = __builtin_amdgcn_mfma_f32_16x16x32_bf16(Ahi[q], Bhi, acc, 0, 0, 0);
      // C: row(b) = kb*4+i, col(m) = lm
#pragma unroll
      for (int i = 0; i < 4; ++i)
        tr[((kb * 4 + i) * 16 + lm) * 17 + uq] = acc[i];
    }
    __syncthreads();                 // C: tr(c) visible; MaL(c) reads done

    // ---- emit role: (b=gb, m=m0+ml), 16 u ----
    const int gm = m0 + ml;
    const bool dg = (gm == gb);
    const float* trow = &tr[(bl * 16 + ml) * 17];
    float* wp = wb + (size_t)gm * 512;
#pragma unroll
    for (int q = 0; q < 4; ++q) {
      float rr[4] = {rv[q].x, rv[q].y, rv[q].z, rv[q].w};
      float sv[4];
#pragma unroll
      for (int e = 0; e < 4; ++e) {
        const int u = 4 * q + e;
        float p;
        if ((rr[e] < 0.1f) | dg) p = 0.f;
        else                     p = __expf(trow[u] * tvf[u]);
        sv[e] = p;
        Ls[u] += p;
      }
      *reinterpret_cast<float4*>(wp + 4 * q) =
          make_float4(sv[0], sv[1], sv[2], sv[3]);
    }
  }

  // ---- merge (ml, ml^8) partners; write IL ----
  float tot[16];
#pragma unroll
  for (int u = 0; u < 16; ++u)
    tot[u] = Ls[u] + __shfl_xor(Ls[u], 8, 64);
  if (ml < 8) {
#pragma unroll
    for (int u = 0; u < 16; ++u)
      stats[((size_t)gb * 512 + u0 + u) * 32 + ml] = 1.0f / (8.0f * tot[u]);
  }
}

// ---------------- K3b v3: w = p*IL + outputs, 16b x 16u blocks ----------------
__global__ __launch_bounds__(256) void emit_outputs_v3(
    const float* __restrict__ mo,    // [512][512][32]
    float* __restrict__ w,           // in: p values, out: final w
    float* __restrict__ outs)        // in: stats cells (IL), out: outputs
{
  __shared__ float MoL[8 * 16 * 32];
  __shared__ float E[8 * 16 * 17];
  const int u0 = blockIdx.x * 16;
  const int b0 = blockIdx.y * 16;
  const int t  = threadIdx.x;
  const int ab = t >> 4, am = (t >> 1) & 7, uh = t & 1;
  const int pu = t >> 4, bq = (t >> 2) & 3, dh = t & 3;

  float Sreg[8];
  {
    const float* cb = outs + ((size_t)(b0 + ab) * 512 + u0 + uh * 8) * 32;
#pragma unroll
    for (int j = 0; j < 8; ++j) Sreg[j] = cb[j * 32 + am];
  }

  float4 acc[4][2];
#pragma unroll
  for (int i = 0; i < 4; ++i) {
    acc[i][0] = make_float4(0.f, 0.f, 0.f, 0.f);
    acc[i][1] = make_float4(0.f, 0.f, 0.f, 0.f);
  }

  float* wbase = w + (size_t)(b0 + ab) * 262144 + u0 + uh * 8;   // + m*512

  const float* msrc0;  const float* msrc1;  const float* msrc2;  const float* msrc3;
  int loff0, loff1, loff2, loff3;
  {
    int P, mm, uu, dq;
    P = t;          mm = P >> 7; uu = (P >> 3) & 15; dq = P & 7;
    msrc0 = mo + (size_t)mm * 16384 + (size_t)(u0 + uu) * 32 + (dq ^ (uu & 7)) * 4;
    loff0 = P * 4;
    P = 256 + t;    mm = P >> 7; uu = (P >> 3) & 15; dq = P & 7;
    msrc1 = mo + (size_t)mm * 16384 + (size_t)(u0 + uu) * 32 + (dq ^ (uu & 7)) * 4;
    loff1 = P * 4;
    P = 512 + t;    mm = P >> 7; uu = (P >> 3) & 15; dq = P & 7;
    msrc2 = mo + (size_t)mm * 16384 + (size_t)(u0 + uu) * 32 + (dq ^ (uu & 7)) * 4;
    loff2 = P * 4;
    P = 768 + t;    mm = P >> 7; uu = (P >> 3) & 15; dq = P & 7;
    msrc3 = mo + (size_t)mm * 16384 + (size_t)(u0 + uu) * 32 + (dq ^ (uu & 7)) * 4;
    loff3 = P * 4;
  }

  float4 wpre0, wpre1, smo0, smo1, smo2, smo3;
  {
    const float* wp = wbase + (size_t)am * 512;
    wpre0 = *reinterpret_cast<const float4*>(wp);
    wpre1 = *reinterpret_cast<const float4*>(wp + 4);
    smo0 = *reinterpret_cast<const float4*>(msrc0);
    smo1 = *reinterpret_cast<const float4*>(msrc1);
    smo2 = *reinterpret_cast<const float4*>(msrc2);
    smo3 = *reinterpret_cast<const float4*>(msrc3);
  }

#pragma unroll 1
  for (int c = 0; c < 64; ++c) {
    const int mc = c * 8;
    if (c) __syncthreads();            // phase B of c-1 done with E/MoL

    // ---- phase A: v = p*IL, write w + E; ds_write staged mo ----
    {
      float* wp = wbase + (size_t)(mc + am) * 512;
      float s0[4] = {wpre0.x, wpre0.y, wpre0.z, wpre0.w};
      float s1[4] = {wpre1.x, wpre1.y, wpre1.z, wpre1.w};
#pragma unroll
      for (int e2 = 0; e2 < 4; ++e2) {
        float v = s0[e2] * Sreg[e2];
        s0[e2] = v;
        E[(am * 16 + uh * 8 + e2) * 17 + ab] = v;
      }
#pragma unroll
      for (int e2 = 0; e2 < 4; ++e2) {
        float v = s1[e2] * Sreg[4 + e2];
        s1[e2] = v;
        E[(am * 16 + uh * 8 + 4 + e2) * 17 + ab] = v;
      }
      *reinterpret_cast<float4*>(wp)     = make_float4(s0[0], s0[1], s0[2], s0[3]);
      *reinterpret_cast<float4*>(wp + 4) = make_float4(s1[0], s1[1], s1[2], s1[3]);
    }
    *reinterpret_cast<float4*>(&MoL[loff0]) = smo0;
    *reinterpret_cast<float4*>(&MoL[loff1]) = smo1;
    *reinterpret_cast<float4*>(&MoL[loff2]) = smo2;
    *reinterpret_cast<float4*>(&MoL[loff3]) = smo3;
    __syncthreads();                   // E + MoL ready

    // ---- issue prefetch for chunk c+1 ----
    if (c < 63) {
      const float* wp = wbase + (size_t)(mc + 8 + am) * 512;
      wpre0 = *reinterpret_cast<const float4*>(wp);
      wpre1 = *reinterpret_cast<const float4*>(wp + 4);
      const size_t moff = (size_t)(mc + 8) * 16384;
      smo0 = *reinterpret_cast<const float4*>(msrc0 + moff);
      smo1 = *reinterpret_cast<const float4*>(msrc1 + moff);
      smo2 = *reinterpret_cast<const float4*>(msrc2 + moff);
      smo3 = *reinterpret_cast<const float4*>(msrc3 + moff);
    }

    // ---- phase B: acc[4b][8d] += E[m][pu][4b] * Mo[m][pu][8d] ----
#pragma unroll
    for (int m = 0; m < 8; ++m) {
      float4 ef = *reinterpret_cast<const float4*>(&E[(m * 16 + pu) * 17 + 4 * bq]);
      float4 v0 = *reinterpret_cast<const float4*>(
          &MoL[(m * 16 + pu) * 32 + (((2 * dh) ^ (pu & 7)) * 4)]);
      float4 v1 = *reinterpret_cast<const float4*>(
          &MoL[(m * 16 + pu) * 32 + (((2 * dh + 1) ^ (pu & 7)) * 4)]);
      float es[4] = {ef.x, ef.y, ef.z, ef.w};
#pragma unroll
      for (int i = 0; i < 4; ++i) {
        acc[i][0].x = fmaf(es[i], v0.x, acc[i][0].x);
        acc[i][0].y = fmaf(es[i], v0.y, acc[i][0].y);
        acc[i][0].z = fmaf(es[i], v0.z, acc[i][0].z);
        acc[i][0].w = fmaf(es[i], v0.w, acc[i][0].w);
        acc[i][1].x = fmaf(es[i], v1.x, acc[i][1].x);
        acc[i][1].y = fmaf(es[i], v1.y, acc[i][1].y);
        acc[i][1].z = fmaf(es[i], v1.z, acc[i][1].z);
        acc[i][1].w = fmaf(es[i], v1.w, acc[i][1].w);
      }
    }
  }

  // epilogue: overwrite stats cells with final outputs
#pragma unroll
  for (int i = 0; i < 4; ++i) {
    float* dst = outs + ((size_t)(b0 + 4 * bq + i) * 512 + u0 + pu) * 32 + 8 * dh;
    *reinterpret_cast<float4*>(dst)     = acc[i][0];
    *reinterpret_cast<float4*>(dst + 4) = acc[i][1];
  }
}

extern "C" void kernel_launch(void* const* d_in, const int* in_sizes, int n_in,
                              void* d_out, int out_size, void* d_ws, size_t ws_size,
                              hipStream_t stream) {
  const float* x    = (const float*)d_in[0];   // [512][4096]
  const float* ma   = (const float*)d_in[1];   // [512][512][32]
  const float* mo   = (const float*)d_in[2];   // [512][512][32]
  const float* rnd  = (const float*)d_in[3];   // [512][512][512]
  const float* w1   = (const float*)d_in[4];   // [8][512][256]
  const float* b1   = (const float*)d_in[5];   // [8][256]
  const float* w2   = (const float*)d_in[6];   // [8][256][2048]
  const float* b2   = (const float*)d_in[7];   // [8][2048]
  const float* temp = (const float*)d_in[8];   // [512]

  float* out  = (float*)d_out;
  float* att  = out;                  // 8388608
  float* ga   = out + 8388608;        // 1048576
  float* wbuf = out + 9437184;        // 134217728
  float* outs = out + 143654912;      // 8388608

  gemm_split<<<dim3(32, 8), 256, 0, stream>>>(x, 4096, 512, w1, 256, b1, ga, 2048);
  gemm_split<<<dim3(256, 8), 256, 0, stream>>>(ga, 2048, 256, w2, 2048, b2, att, 16384);
  scores_mfma_v3<<<dim3(32, 32), 256, 0, stream>>>(att, ma, rnd, temp, wbuf, outs);
  emit_outputs_v3<<<dim3(32, 32), 256, 0, stream>>>(mo, wbuf, outs);
}

// Round 11
// 958.886 us; speedup vs baseline: 1.2444x; 1.2444x over previous
//
#include <hip/hip_runtime.h>
#include <math.h>

#define NEGBIG (-1e30f)
#define GLB_PTR(x) ((const __attribute__((address_space(1))) void*)(x))
#define LDS_PTR(x) ((__attribute__((address_space(3))) void*)(x))

typedef __bf16 bf16x8 __attribute__((ext_vector_type(8)));
typedef float  f32x4  __attribute__((ext_vector_type(4)));

// Sizes: B=512, S=8, U=512, D=32, G=8, DIM_IN=4096, DAG=2048
// out layout: att[512*16384] | ga[512*2048] | w[512^3] | outputs[512*16384]
// No-max softmax: scores kernel stores p = exp(s) (masked -> 0) into the w
// region and accumulates L_g; stats cell (b,u) floats [0..7] = 1/(8 L_g).
// emit kernel: w = p * IL_g + PV accumulation; overwrites stats cells.

// ---------------- K1/K2: per-split fp32 GEMM (64x64 tile, Kstep 16) ----------------
__global__ __launch_bounds__(256) void gemm_split(
    const float* __restrict__ A, int lda, int Ksz,
    const float* __restrict__ Bw, int NS,
    const float* __restrict__ bias,
    float* __restrict__ C, int ldc)
{
  const int n0 = blockIdx.x * 64;
  const int b0 = blockIdx.y * 64;
  const int s  = n0 / NS;
  const float* Bp = Bw + (size_t)s * Ksz * NS;
  const int nloc0 = n0 - s * NS;
  const int acol0 = s * Ksz;

  __shared__ float As[16][64];
  __shared__ float Bs[16][64];

  const int t  = threadIdx.x;
  const int tb = t & 15, tn = t >> 4;
  float acc[4][4] = {};

  for (int k0 = 0; k0 < Ksz; k0 += 16) {
    {
      int r = t & 63, g = t >> 6;
      float4 v = *reinterpret_cast<const float4*>(
          A + (size_t)(b0 + r) * lda + acol0 + k0 + 4 * g);
      As[4*g+0][r] = v.x; As[4*g+1][r] = v.y; As[4*g+2][r] = v.z; As[4*g+3][r] = v.w;
    }
    {
      int kk = t >> 4, n4 = t & 15;
      float4 v = *reinterpret_cast<const float4*>(
          Bp + (size_t)(k0 + kk) * NS + nloc0 + 4 * n4);
      *reinterpret_cast<float4*>(&Bs[kk][4*n4]) = v;
    }
    __syncthreads();
#pragma unroll
    for (int k = 0; k < 16; ++k) {
      float4 a4 = *reinterpret_cast<const float4*>(&As[k][4*tb]);
      float4 b4 = *reinterpret_cast<const float4*>(&Bs[k][4*tn]);
      float av[4] = {a4.x, a4.y, a4.z, a4.w};
      float bv[4] = {b4.x, b4.y, b4.z, b4.w};
#pragma unroll
      for (int i = 0; i < 4; ++i)
#pragma unroll
        for (int j = 0; j < 4; ++j)
          acc[i][j] = fmaf(av[i], bv[j], acc[i][j]);
    }
    __syncthreads();
  }
#pragma unroll
  for (int i = 0; i < 4; ++i) {
    int row = b0 + 4*tb + i;
    int col = n0 + 4*tn;
    float4 o;
    o.x = acc[i][0] + bias[col + 0];
    o.y = acc[i][1] + bias[col + 1];
    o.z = acc[i][2] + bias[col + 2];
    o.w = acc[i][3] + bias[col + 3];
    *reinterpret_cast<float4*>(C + (size_t)row * ldc + col) = o;
  }
}

// ---------------- K3a (MFMA v4): p = exp(masked score) + group sums ----------------
// Block 16b x 16u, 16-m chunks, LDS = 32 KB MaL only (5 blocks/CU).
// Everything stays in the MFMA C domain -- no transpose, no role swap:
// lane l = (kb = l>>4, lm = l&15) of wave w owns C[b = kb*4+i][m = lm][u = 4w+q].
// ma staged by global_load_lds, slot s=(m<<7)+(u<<3)+dqS holds d-quad dqS^(m&7)
// (4-way bank aliasing on B-frag reads -- measured tolerable in r9).
// Per chunk: {barrier (MaL ready); rnd f4 reads (long cover); B-split + 12
// MFMA; barrier (MaL reads done); issue gloads(c+1); emit: mask/exp, f4
// w-writes, Ls[4b][4u] register accumulate (g = lm&7 static)}.
// Epilogue: shfl_xor(8) merge; lanes lm<8 write IL = 1/(8L) to stats cell [g].
__global__ __launch_bounds__(256) void scores_mfma_v4(
    const float* __restrict__ att,   // [512][512][32]
    const float* __restrict__ ma,    // [512][512][32]
    const float* __restrict__ rnd,   // [512][512][512]
    const float* __restrict__ temp,  // [512]
    float* __restrict__ wout,        // [512][512][512] <- p values
    float* __restrict__ stats)       // outs region base
{
  __shared__ float MaL[2048 * 4];    // 32 KB staged ma chunk (f4 slots)
  // XCD-chunked decode: cluster same-u-tile blocks per XCD for ma L2 reuse
  const int bid = blockIdx.x;
  const int id  = ((bid & 7) << 7) | (bid >> 3);   // 1024 % 8 == 0
  const int u0  = (id >> 5) * 16;
  const int b0  = (id & 31) * 16;
  const int t   = threadIdx.x;
  const int w   = t >> 6, l = t & 63;
  const int lm  = l & 15, kb = l >> 4;

  // temperatures for this wave's 4 u's only
  float tv[4];
#pragma unroll
  for (int q = 0; q < 4; ++q) tv[q] = temp[u0 + 4 * w + q];

  // A-fragments (att) for the wave's 4 u's, split hi/lo bf16, loaded once
  bf16x8 Ahi[4], Alo[4];
#pragma unroll
  for (int q = 0; q < 4; ++q) {
    const float* ap = att + (size_t)(b0 + lm) * 16384
                    + (size_t)(u0 + 4 * w + q) * 32 + kb * 8;
    float4 a0 = *reinterpret_cast<const float4*>(ap);
    float4 a1 = *reinterpret_cast<const float4*>(ap + 4);
    float af[8] = {a0.x, a0.y, a0.z, a0.w, a1.x, a1.y, a1.z, a1.w};
#pragma unroll
    for (int j = 0; j < 8; ++j) {
      __bf16 h = (__bf16)af[j];
      Ahi[q][j] = h;
      Alo[q][j] = (__bf16)(af[j] - (float)h);
    }
  }

  // staging source offsets: slot s = k*256 + t holds ma(m=s>>7, u=(s>>3)&15,
  // d-quad = (s&7) ^ (m&7)) of the current chunk
  int off[8];
#pragma unroll
  for (int k = 0; k < 8; ++k) {
    int s = k * 256 + t;
    int mm = s >> 7, uu = (s >> 3) & 15, d4s = s & 7;
    off[k] = mm * 16384 + (u0 + uu) * 32 + ((d4s ^ (mm & 7)) << 2);
  }

  float Ls[4][4];                    // [b-sub i][u-sub q]
#pragma unroll
  for (int i = 0; i < 4; ++i)
#pragma unroll
    for (int q = 0; q < 4; ++q) Ls[i][q] = 0.f;

  // per-lane rnd/w bases: b = b0 + kb*4 + i, m = m0 + lm, u = u0 + 4w
  const float* rbl = rnd  + (size_t)(b0 + kb * 4) * 262144
                   + (size_t)lm * 512 + u0 + 4 * w;
  float*       wbl = wout + (size_t)(b0 + kb * 4) * 262144
                   + (size_t)lm * 512 + u0 + 4 * w;

  // prologue: stage chunk 0
#pragma unroll
  for (int k = 0; k < 8; ++k)
    __builtin_amdgcn_global_load_lds(GLB_PTR(ma + (size_t)off[k]),
                                     LDS_PTR(&MaL[(k * 256 + w * 64) * 4]), 16, 0, 0);

#pragma unroll 1
  for (int c = 0; c < 32; ++c) {
    const int m0 = c * 16;
    __syncthreads();                 // MaL(c) drained & free for reads

    // rnd for this chunk's lane-owned cells (consumed at emit -- long cover)
    float4 rv[4];
#pragma unroll
    for (int i = 0; i < 4; ++i)
      rv[i] = *reinterpret_cast<const float4*>(rbl + (size_t)i * 262144
                                               + (size_t)m0 * 512);

    // ---- B-frag split + 12 MFMAs (3-term split x 4 u) ----
    f32x4 acc[4];
#pragma unroll
    for (int q = 0; q < 4; ++q) {
      const int uq = 4 * w + q;
      const int s0 = (lm << 7) + (uq << 3) + ((2 * kb)     ^ (lm & 7));
      const int s1 = (lm << 7) + (uq << 3) + ((2 * kb + 1) ^ (lm & 7));
      float4 g0 = *reinterpret_cast<const float4*>(&MaL[s0 * 4]);
      float4 g1 = *reinterpret_cast<const float4*>(&MaL[s1 * 4]);
      float bf[8] = {g0.x, g0.y, g0.z, g0.w, g1.x, g1.y, g1.z, g1.w};
      bf16x8 Bhi, Blo;
#pragma unroll
      for (int j = 0; j < 8; ++j) {
        __bf16 h = (__bf16)bf[j];
        Bhi[j] = h;
        Blo[j] = (__bf16)(bf[j] - (float)h);
      }
      f32x4 a = {0.f, 0.f, 0.f, 0.f};
      a = __builtin_amdgcn_mfma_f32_16x16x32_bf16(Ahi[q], Blo, a, 0, 0, 0);
      a = __builtin_amdgcn_mfma_f32_16x16x32_bf16(Alo[q], Bhi, a, 0, 0, 0);
      a = __builtin_amdgcn_mfma_f32_16x16x32_bf16(Ahi[q], Bhi, a, 0, 0, 0);
      acc[q] = a;
    }
    __syncthreads();                 // all waves done reading MaL(c)

    // issue next chunk's staging: covered by the emit phase below
    if (c < 31) {
#pragma unroll
      for (int k = 0; k < 8; ++k)
        __builtin_amdgcn_global_load_lds(
            GLB_PTR(ma + (size_t)off[k] + (size_t)(m0 + 16) * 16384),
            LDS_PTR(&MaL[(k * 256 + w * 64) * 4]), 16, 0, 0);
    }

    // ---- emit in C layout: lane owns (b = kb*4+i, m = m0+lm, u = 4w+q) ----
    const int gm = m0 + lm;
#pragma unroll
    for (int i = 0; i < 4; ++i) {
      const int gb = b0 + kb * 4 + i;
      const bool dg = (gm == gb);
      float rr[4] = {rv[i].x, rv[i].y, rv[i].z, rv[i].w};
      float pv[4];
#pragma unroll
      for (int q = 0; q < 4; ++q) {
        float p;
        if ((rr[q] < 0.1f) | dg) p = 0.f;
        else                     p = __expf(acc[q][i] * tv[q]);
        pv[q] = p;
        Ls[i][q] += p;
      }
      *reinterpret_cast<float4*>(wbl + (size_t)i * 262144 + (size_t)m0 * 512) =
          make_float4(pv[0], pv[1], pv[2], pv[3]);
    }
  }

  // ---- merge lm <-> lm^8 partners (same g = lm&7); lm<8 writes IL ----
#pragma unroll
  for (int i = 0; i < 4; ++i)
#pragma unroll
    for (int q = 0; q < 4; ++q)
      Ls[i][q] += __shfl_xor(Ls[i][q], 8, 64);
  if (lm < 8) {
#pragma unroll
    for (int i = 0; i < 4; ++i)
#pragma unroll
      for (int q = 0; q < 4; ++q)
        stats[((size_t)(b0 + kb * 4 + i) * 512 + u0 + 4 * w + q) * 32 + lm] =
            1.0f / (8.0f * Ls[i][q]);
  }
}

// ---------------- K3b v3: w = p*IL + outputs, 16b x 16u blocks ----------------
__global__ __launch_bounds__(256) void emit_outputs_v3(
    const float* __restrict__ mo,    // [512][512][32]
    float* __restrict__ w,           // in: p values, out: final w
    float* __restrict__ outs)        // in: stats cells (IL), out: outputs
{
  __shared__ float MoL[8 * 16 * 32];
  __shared__ float E[8 * 16 * 17];
  const int u0 = blockIdx.x * 16;
  const int b0 = blockIdx.y * 16;
  const int t  = threadIdx.x;
  const int ab = t >> 4, am = (t >> 1) & 7, uh = t & 1;
  const int pu = t >> 4, bq = (t >> 2) & 3, dh = t & 3;

  float Sreg[8];
  {
    const float* cb = outs + ((size_t)(b0 + ab) * 512 + u0 + uh * 8) * 32;
#pragma unroll
    for (int j = 0; j < 8; ++j) Sreg[j] = cb[j * 32 + am];
  }

  float4 acc[4][2];
#pragma unroll
  for (int i = 0; i < 4; ++i) {
    acc[i][0] = make_float4(0.f, 0.f, 0.f, 0.f);
    acc[i][1] = make_float4(0.f, 0.f, 0.f, 0.f);
  }

  float* wbase = w + (size_t)(b0 + ab) * 262144 + u0 + uh * 8;   // + m*512

  const float* msrc0;  const float* msrc1;  const float* msrc2;  const float* msrc3;
  int loff0, loff1, loff2, loff3;
  {
    int P, mm, uu, dq;
    P = t;          mm = P >> 7; uu = (P >> 3) & 15; dq = P & 7;
    msrc0 = mo + (size_t)mm * 16384 + (size_t)(u0 + uu) * 32 + (dq ^ (uu & 7)) * 4;
    loff0 = P * 4;
    P = 256 + t;    mm = P >> 7; uu = (P >> 3) & 15; dq = P & 7;
    msrc1 = mo + (size_t)mm * 16384 + (size_t)(u0 + uu) * 32 + (dq ^ (uu & 7)) * 4;
    loff1 = P * 4;
    P = 512 + t;    mm = P >> 7; uu = (P >> 3) & 15; dq = P & 7;
    msrc2 = mo + (size_t)mm * 16384 + (size_t)(u0 + uu) * 32 + (dq ^ (uu & 7)) * 4;
    loff2 = P * 4;
    P = 768 + t;    mm = P >> 7; uu = (P >> 3) & 15; dq = P & 7;
    msrc3 = mo + (size_t)mm * 16384 + (size_t)(u0 + uu) * 32 + (dq ^ (uu & 7)) * 4;
    loff3 = P * 4;
  }

  float4 wpre0, wpre1, smo0, smo1, smo2, smo3;
  {
    const float* wp = wbase + (size_t)am * 512;
    wpre0 = *reinterpret_cast<const float4*>(wp);
    wpre1 = *reinterpret_cast<const float4*>(wp + 4);
    smo0 = *reinterpret_cast<const float4*>(msrc0);
    smo1 = *reinterpret_cast<const float4*>(msrc1);
    smo2 = *reinterpret_cast<const float4*>(msrc2);
    smo3 = *reinterpret_cast<const float4*>(msrc3);
  }

#pragma unroll 1
  for (int c = 0; c < 64; ++c) {
    const int mc = c * 8;
    if (c) __syncthreads();            // phase B of c-1 done with E/MoL

    // ---- phase A: v = p*IL, write w + E; ds_write staged mo ----
    {
      float* wp = wbase + (size_t)(mc + am) * 512;
      float s0[4] = {wpre0.x, wpre0.y, wpre0.z, wpre0.w};
      float s1[4] = {wpre1.x, wpre1.y, wpre1.z, wpre1.w};
#pragma unroll
      for (int e2 = 0; e2 < 4; ++e2) {
        float v = s0[e2] * Sreg[e2];
        s0[e2] = v;
        E[(am * 16 + uh * 8 + e2) * 17 + ab] = v;
      }
#pragma unroll
      for (int e2 = 0; e2 < 4; ++e2) {
        float v = s1[e2] * Sreg[4 + e2];
        s1[e2] = v;
        E[(am * 16 + uh * 8 + 4 + e2) * 17 + ab] = v;
      }
      *reinterpret_cast<float4*>(wp)     = make_float4(s0[0], s0[1], s0[2], s0[3]);
      *reinterpret_cast<float4*>(wp + 4) = make_float4(s1[0], s1[1], s1[2], s1[3]);
    }
    *reinterpret_cast<float4*>(&MoL[loff0]) = smo0;
    *reinterpret_cast<float4*>(&MoL[loff1]) = smo1;
    *reinterpret_cast<float4*>(&MoL[loff2]) = smo2;
    *reinterpret_cast<float4*>(&MoL[loff3]) = smo3;
    __syncthreads();                   // E + MoL ready

    // ---- issue prefetch for chunk c+1 ----
    if (c < 63) {
      const float* wp = wbase + (size_t)(mc + 8 + am) * 512;
      wpre0 = *reinterpret_cast<const float4*>(wp);
      wpre1 = *reinterpret_cast<const float4*>(wp + 4);
      const size_t moff = (size_t)(mc + 8) * 16384;
      smo0 = *reinterpret_cast<const float4*>(msrc0 + moff);
      smo1 = *reinterpret_cast<const float4*>(msrc1 + moff);
      smo2 = *reinterpret_cast<const float4*>(msrc2 + moff);
      smo3 = *reinterpret_cast<const float4*>(msrc3 + moff);
    }

    // ---- phase B: acc[4b][8d] += E[m][pu][4b] * Mo[m][pu][8d] ----
#pragma unroll
    for (int m = 0; m < 8; ++m) {
      float4 ef = *reinterpret_cast<const float4*>(&E[(m * 16 + pu) * 17 + 4 * bq]);
      float4 v0 = *reinterpret_cast<const float4*>(
          &MoL[(m * 16 + pu) * 32 + (((2 * dh) ^ (pu & 7)) * 4)]);
      float4 v1 = *reinterpret_cast<const float4*>(
          &MoL[(m * 16 + pu) * 32 + (((2 * dh + 1) ^ (pu & 7)) * 4)]);
      float es[4] = {ef.x, ef.y, ef.z, ef.w};
#pragma unroll
      for (int i = 0; i < 4; ++i) {
        acc[i][0].x = fmaf(es[i], v0.x, acc[i][0].x);
        acc[i][0].y = fmaf(es[i], v0.y, acc[i][0].y);
        acc[i][0].z = fmaf(es[i], v0.z, acc[i][0].z);
        acc[i][0].w = fmaf(es[i], v0.w, acc[i][0].w);
        acc[i][1].x = fmaf(es[i], v1.x, acc[i][1].x);
        acc[i][1].y = fmaf(es[i], v1.y, acc[i][1].y);
        acc[i][1].z = fmaf(es[i], v1.z, acc[i][1].z);
        acc[i][1].w = fmaf(es[i], v1.w, acc[i][1].w);
      }
    }
  }

  // epilogue: overwrite stats cells with final outputs
#pragma unroll
  for (int i = 0; i < 4; ++i) {
    float* dst = outs + ((size_t)(b0 + 4 * bq + i) * 512 + u0 + pu) * 32 + 8 * dh;
    *reinterpret_cast<float4*>(dst)     = acc[i][0];
    *reinterpret_cast<float4*>(dst + 4) = acc[i][1];
  }
}

extern "C" void kernel_launch(void* const* d_in, const int* in_sizes, int n_in,
                              void* d_out, int out_size, void* d_ws, size_t ws_size,
                              hipStream_t stream) {
  const float* x    = (const float*)d_in[0];   // [512][4096]
  const float* ma   = (const float*)d_in[1];   // [512][512][32]
  const float* mo   = (const float*)d_in[2];   // [512][512][32]
  const float* rnd  = (const float*)d_in[3];   // [512][512][512]
  const float* w1   = (const float*)d_in[4];   // [8][512][256]
  const float* b1   = (const float*)d_in[5];   // [8][256]
  const float* w2   = (const float*)d_in[6];   // [8][256][2048]
  const float* b2   = (const float*)d_in[7];   // [8][2048]
  const float* temp = (const float*)d_in[8];   // [512]

  float* out  = (float*)d_out;
  float* att  = out;                  // 8388608
  float* ga   = out + 8388608;        // 1048576
  float* wbuf = out + 9437184;        // 134217728
  float* outs = out + 143654912;      // 8388608

  gemm_split<<<dim3(32, 8), 256, 0, stream>>>(x, 4096, 512, w1, 256, b1, ga, 2048);
  gemm_split<<<dim3(256, 8), 256, 0, stream>>>(ga, 2048, 256, w2, 2048, b2, att, 16384);
  scores_mfma_v4<<<dim3(1024), 256, 0, stream>>>(att, ma, rnd, temp, wbuf, outs);
  emit_outputs_v3<<<dim3(32, 32), 256, 0, stream>>>(mo, wbuf, outs);
}

// Round 12
// 822.508 us; speedup vs baseline: 1.4507x; 1.1658x over previous
//
#include <hip/hip_runtime.h>
#include <math.h>

#define NEGBIG (-1e30f)
#define GLB_PTR(x) ((const __attribute__((address_space(1))) void*)(x))
#define LDS_PTR(x) ((__attribute__((address_space(3))) void*)(x))

typedef __bf16 bf16x8 __attribute__((ext_vector_type(8)));
typedef float  f32x4  __attribute__((ext_vector_type(4)));

// Sizes: B=512, S=8, U=512, D=32, G=8, DIM_IN=4096, DAG=2048
// out layout: att[512*16384] | ga[512*2048] | w[512^3] | outputs[512*16384]
// No-max softmax: scores kernel stores p = exp(s) (masked -> 0) into the w
// region and accumulates L_g; stats cell (b,u) floats [0..7] = 1/(8 L_g).
// emit kernel: w = p * IL_g + PV accumulation; overwrites stats cells.

// ---------------- K1/K2: per-split fp32 GEMM (64x64 tile, Kstep 16) ----------------
__global__ __launch_bounds__(256) void gemm_split(
    const float* __restrict__ A, int lda, int Ksz,
    const float* __restrict__ Bw, int NS,
    const float* __restrict__ bias,
    float* __restrict__ C, int ldc)
{
  const int n0 = blockIdx.x * 64;
  const int b0 = blockIdx.y * 64;
  const int s  = n0 / NS;
  const float* Bp = Bw + (size_t)s * Ksz * NS;
  const int nloc0 = n0 - s * NS;
  const int acol0 = s * Ksz;

  __shared__ float As[16][64];
  __shared__ float Bs[16][64];

  const int t  = threadIdx.x;
  const int tb = t & 15, tn = t >> 4;
  float acc[4][4] = {};

  for (int k0 = 0; k0 < Ksz; k0 += 16) {
    {
      int r = t & 63, g = t >> 6;
      float4 v = *reinterpret_cast<const float4*>(
          A + (size_t)(b0 + r) * lda + acol0 + k0 + 4 * g);
      As[4*g+0][r] = v.x; As[4*g+1][r] = v.y; As[4*g+2][r] = v.z; As[4*g+3][r] = v.w;
    }
    {
      int kk = t >> 4, n4 = t & 15;
      float4 v = *reinterpret_cast<const float4*>(
          Bp + (size_t)(k0 + kk) * NS + nloc0 + 4 * n4);
      *reinterpret_cast<float4*>(&Bs[kk][4*n4]) = v;
    }
    __syncthreads();
#pragma unroll
    for (int k = 0; k < 16; ++k) {
      float4 a4 = *reinterpret_cast<const float4*>(&As[k][4*tb]);
      float4 b4 = *reinterpret_cast<const float4*>(&Bs[k][4*tn]);
      float av[4] = {a4.x, a4.y, a4.z, a4.w};
      float bv[4] = {b4.x, b4.y, b4.z, b4.w};
#pragma unroll
      for (int i = 0; i < 4; ++i)
#pragma unroll
        for (int j = 0; j < 4; ++j)
          acc[i][j] = fmaf(av[i], bv[j], acc[i][j]);
    }
    __syncthreads();
  }
#pragma unroll
  for (int i = 0; i < 4; ++i) {
    int row = b0 + 4*tb + i;
    int col = n0 + 4*tn;
    float4 o;
    o.x = acc[i][0] + bias[col + 0];
    o.y = acc[i][1] + bias[col + 1];
    o.z = acc[i][2] + bias[col + 2];
    o.w = acc[i][3] + bias[col + 3];
    *reinterpret_cast<float4*>(C + (size_t)row * ldc + col) = o;
  }
}

// ---------------- K3a (MFMA v5): p = exp(masked score) + group sums ----------------
// Block 16b x 16u, 16-m chunks. MFMA compute (r9) + COALESCED emit (r8 keying).
// ma staged by global_load_lds, slot s=(m<<7)+(u<<3)+dqS holds d-quad dqS^(m&7)
// (source-side swizzle; B-frag reads ~2-way). Wave w owns u 4w..4w+3; A-frags
// (att) split hi/lo bf16 in regs once; 3 MFMAs/u; C -> tr[row*17 + u'],
// row = b*16+m (b=kb*4+i, m=lm), u' = u ^ ((row>>6)<<2) (<=2-way both sides).
// Emit: thread (eu=t&15, eb=t>>4) owns (b0+eb, u0+eu) for the chunk's 16 m:
// tr reads conflict-free, rnd scalar loads + w scalar stores COALESCED
// (4 lines/inst), Ls[8] thread-local (g=j&7 static), stats written directly.
// Per chunk: {bar A; MFMA->tr; bar B; issue gloads(c+1)+rnd(c+1); emit(c)}.
__global__ __launch_bounds__(256) void scores_mfma_v5(
    const float* __restrict__ att,   // [512][512][32]
    const float* __restrict__ ma,    // [512][512][32]
    const float* __restrict__ rnd,   // [512][512][512]
    const float* __restrict__ temp,  // [512]
    float* __restrict__ wout,        // [512][512][512] <- p values
    float* __restrict__ stats)       // outs region base
{
  __shared__ float MaL[2048 * 4];    // 32 KB staged ma chunk (f4 slots)
  __shared__ float tr[256 * 17];     // 17 KB C transpose
  const int b0 = blockIdx.x * 16;
  const int u0 = blockIdx.y * 16;
  const int t  = threadIdx.x;
  const int w  = t >> 6, l = t & 63;
  const int lm = l & 15, kb = l >> 4;      // MFMA decode: m / k-block
  const int eu = t & 15, eb = t >> 4;      // emit decode: u / b
  const int gbe = b0 + eb;

  const float tmp = temp[u0 + eu];         // emit's single temperature

  // A-fragments (att) for the wave's 4 u's, split hi/lo bf16, loaded once
  bf16x8 Ahi[4], Alo[4];
#pragma unroll
  for (int q = 0; q < 4; ++q) {
    const float* ap = att + (size_t)(b0 + lm) * 16384
                    + (size_t)(u0 + 4 * w + q) * 32 + kb * 8;
    float4 a0 = *reinterpret_cast<const float4*>(ap);
    float4 a1 = *reinterpret_cast<const float4*>(ap + 4);
    float af[8] = {a0.x, a0.y, a0.z, a0.w, a1.x, a1.y, a1.z, a1.w};
#pragma unroll
    for (int j = 0; j < 8; ++j) {
      __bf16 h = (__bf16)af[j];
      Ahi[q][j] = h;
      Alo[q][j] = (__bf16)(af[j] - (float)h);
    }
  }

  // staging source offsets: slot s = k*256 + t holds ma(m=s>>7, u=(s>>3)&15,
  // d-quad = (s&7) ^ (m&7)) of the current chunk
  int off[8];
#pragma unroll
  for (int k = 0; k < 8; ++k) {
    int s = k * 256 + t;
    int mm = s >> 7, uu = (s >> 3) & 15, d4s = s & 7;
    off[k] = mm * 16384 + (u0 + uu) * 32 + ((d4s ^ (mm & 7)) << 2);
  }

  float Ls[8];
#pragma unroll
  for (int g = 0; g < 8; ++g) Ls[g] = 0.f;

  const float* rbase = rnd  + (size_t)gbe * 262144 + u0 + eu;   // + m*512
  float*       wbase = wout + (size_t)gbe * 262144 + u0 + eu;

  // prologue: stage chunk 0 + rnd chunk 0
#pragma unroll
  for (int k = 0; k < 8; ++k)
    __builtin_amdgcn_global_load_lds(GLB_PTR(ma + (size_t)off[k]),
                                     LDS_PTR(&MaL[(k * 256 + w * 64) * 4]), 16, 0, 0);
  float rc[16], rn[16];
#pragma unroll
  for (int j = 0; j < 16; ++j) rc[j] = rbase[(size_t)j * 512];

#pragma unroll 1
  for (int c = 0; c < 32; ++c) {
    const int m0 = c * 16;
    __syncthreads();                 // A: MaL(c) drained; tr(c-1) consumed

    // ---- MFMA role: 4 u's of this wave ----
#pragma unroll
    for (int q = 0; q < 4; ++q) {
      const int uq = 4 * w + q;
      const int s0 = (lm << 7) + (uq << 3) + ((2 * kb)     ^ (lm & 7));
      const int s1 = (lm << 7) + (uq << 3) + ((2 * kb + 1) ^ (lm & 7));
      float4 g0 = *reinterpret_cast<const float4*>(&MaL[s0 * 4]);
      float4 g1 = *reinterpret_cast<const float4*>(&MaL[s1 * 4]);
      float bf[8] = {g0.x, g0.y, g0.z, g0.w, g1.x, g1.y, g1.z, g1.w};
      bf16x8 Bhi, Blo;
#pragma unroll
      for (int j = 0; j < 8; ++j) {
        __bf16 h = (__bf16)bf[j];
        Bhi[j] = h;
        Blo[j] = (__bf16)(bf[j] - (float)h);
      }
      f32x4 a = {0.f, 0.f, 0.f, 0.f};
      a = __builtin_amdgcn_mfma_f32_16x16x32_bf16(Ahi[q], Blo, a, 0, 0, 0);
      a = __builtin_amdgcn_mfma_f32_16x16x32_bf16(Alo[q], Bhi, a, 0, 0, 0);
      a = __builtin_amdgcn_mfma_f32_16x16x32_bf16(Ahi[q], Bhi, a, 0, 0, 0);
      // C: b = kb*4+i, m = lm  ->  row = b*16 + m, swizzled u slot
#pragma unroll
      for (int i = 0; i < 4; ++i) {
        const int row = (kb * 4 + i) * 16 + lm;
        tr[row * 17 + (uq ^ ((row >> 6) << 2))] = a[i];
      }
    }
    __syncthreads();                 // B: tr(c) visible; MaL(c) reads done

    // ---- issue chunk c+1 staging + rnd(c+1): covered by emit(c) ----
    if (c < 31) {
#pragma unroll
      for (int k = 0; k < 8; ++k)
        __builtin_amdgcn_global_load_lds(
            GLB_PTR(ma + (size_t)off[k] + (size_t)(m0 + 16) * 16384),
            LDS_PTR(&MaL[(k * 256 + w * 64) * 4]), 16, 0, 0);
#pragma unroll
      for (int j = 0; j < 16; ++j)
        rn[j] = rbase[(size_t)(m0 + 16 + j) * 512];
    }

    // ---- emit role: thread (u = eu, b = eb), 16 m, coalesced IO ----
    const int swz = (eb >> 2) << 2;  // (row>>6) for row = eb*16 + m
    const float* trow = &tr[(eb * 16) * 17 + (eu ^ swz)];
#pragma unroll
    for (int j = 0; j < 16; ++j) {
      const int gm = m0 + j;
      float p;
      if ((rc[j] < 0.1f) | (gm == gbe)) p = 0.f;
      else                              p = __expf(trow[j * 17] * tmp);
      wbase[(size_t)gm * 512] = p;
      Ls[j & 7] += p;
    }
#pragma unroll
    for (int j = 0; j < 16; ++j) rc[j] = rn[j];
  }

  // ---- stats: thread owns (b,u) completely -- direct write, no merge ----
  {
    float* cell = stats + ((size_t)gbe * 512 + u0 + eu) * 32;
#pragma unroll
    for (int g = 0; g < 8; ++g) cell[g] = 1.0f / (8.0f * Ls[g]);
  }
}

// ---------------- K3b v3: w = p*IL + outputs, 16b x 16u blocks ----------------
__global__ __launch_bounds__(256) void emit_outputs_v3(
    const float* __restrict__ mo,    // [512][512][32]
    float* __restrict__ w,           // in: p values, out: final w
    float* __restrict__ outs)        // in: stats cells (IL), out: outputs
{
  __shared__ float MoL[8 * 16 * 32];
  __shared__ float E[8 * 16 * 17];
  const int u0 = blockIdx.x * 16;
  const int b0 = blockIdx.y * 16;
  const int t  = threadIdx.x;
  const int ab = t >> 4, am = (t >> 1) & 7, uh = t & 1;
  const int pu = t >> 4, bq = (t >> 2) & 3, dh = t & 3;

  float Sreg[8];
  {
    const float* cb = outs + ((size_t)(b0 + ab) * 512 + u0 + uh * 8) * 32;
#pragma unroll
    for (int j = 0; j < 8; ++j) Sreg[j] = cb[j * 32 + am];
  }

  float4 acc[4][2];
#pragma unroll
  for (int i = 0; i < 4; ++i) {
    acc[i][0] = make_float4(0.f, 0.f, 0.f, 0.f);
    acc[i][1] = make_float4(0.f, 0.f, 0.f, 0.f);
  }

  float* wbase = w + (size_t)(b0 + ab) * 262144 + u0 + uh * 8;   // + m*512

  const float* msrc0;  const float* msrc1;  const float* msrc2;  const float* msrc3;
  int loff0, loff1, loff2, loff3;
  {
    int P, mm, uu, dq;
    P = t;          mm = P >> 7; uu = (P >> 3) & 15; dq = P & 7;
    msrc0 = mo + (size_t)mm * 16384 + (size_t)(u0 + uu) * 32 + (dq ^ (uu & 7)) * 4;
    loff0 = P * 4;
    P = 256 + t;    mm = P >> 7; uu = (P >> 3) & 15; dq = P & 7;
    msrc1 = mo + (size_t)mm * 16384 + (size_t)(u0 + uu) * 32 + (dq ^ (uu & 7)) * 4;
    loff1 = P * 4;
    P = 512 + t;    mm = P >> 7; uu = (P >> 3) & 15; dq = P & 7;
    msrc2 = mo + (size_t)mm * 16384 + (size_t)(u0 + uu) * 32 + (dq ^ (uu & 7)) * 4;
    loff2 = P * 4;
    P = 768 + t;    mm = P >> 7; uu = (P >> 3) & 15; dq = P & 7;
    msrc3 = mo + (size_t)mm * 16384 + (size_t)(u0 + uu) * 32 + (dq ^ (uu & 7)) * 4;
    loff3 = P * 4;
  }

  float4 wpre0, wpre1, smo0, smo1, smo2, smo3;
  {
    const float* wp = wbase + (size_t)am * 512;
    wpre0 = *reinterpret_cast<const float4*>(wp);
    wpre1 = *reinterpret_cast<const float4*>(wp + 4);
    smo0 = *reinterpret_cast<const float4*>(msrc0);
    smo1 = *reinterpret_cast<const float4*>(msrc1);
    smo2 = *reinterpret_cast<const float4*>(msrc2);
    smo3 = *reinterpret_cast<const float4*>(msrc3);
  }

#pragma unroll 1
  for (int c = 0; c < 64; ++c) {
    const int mc = c * 8;
    if (c) __syncthreads();            // phase B of c-1 done with E/MoL

    // ---- phase A: v = p*IL, write w + E; ds_write staged mo ----
    {
      float* wp = wbase + (size_t)(mc + am) * 512;
      float s0[4] = {wpre0.x, wpre0.y, wpre0.z, wpre0.w};
      float s1[4] = {wpre1.x, wpre1.y, wpre1.z, wpre1.w};
#pragma unroll
      for (int e2 = 0; e2 < 4; ++e2) {
        float v = s0[e2] * Sreg[e2];
        s0[e2] = v;
        E[(am * 16 + uh * 8 + e2) * 17 + ab] = v;
      }
#pragma unroll
      for (int e2 = 0; e2 < 4; ++e2) {
        float v = s1[e2] * Sreg[4 + e2];
        s1[e2] = v;
        E[(am * 16 + uh * 8 + 4 + e2) * 17 + ab] = v;
      }
      *reinterpret_cast<float4*>(wp)     = make_float4(s0[0], s0[1], s0[2], s0[3]);
      *reinterpret_cast<float4*>(wp + 4) = make_float4(s1[0], s1[1], s1[2], s1[3]);
    }
    *reinterpret_cast<float4*>(&MoL[loff0]) = smo0;
    *reinterpret_cast<float4*>(&MoL[loff1]) = smo1;
    *reinterpret_cast<float4*>(&MoL[loff2]) = smo2;
    *reinterpret_cast<float4*>(&MoL[loff3]) = smo3;
    __syncthreads();                   // E + MoL ready

    // ---- issue prefetch for chunk c+1 ----
    if (c < 63) {
      const float* wp = wbase + (size_t)(mc + 8 + am) * 512;
      wpre0 = *reinterpret_cast<const float4*>(wp);
      wpre1 = *reinterpret_cast<const float4*>(wp + 4);
      const size_t moff = (size_t)(mc + 8) * 16384;
      smo0 = *reinterpret_cast<const float4*>(msrc0 + moff);
      smo1 = *reinterpret_cast<const float4*>(msrc1 + moff);
      smo2 = *reinterpret_cast<const float4*>(msrc2 + moff);
      smo3 = *reinterpret_cast<const float4*>(msrc3 + moff);
    }

    // ---- phase B: acc[4b][8d] += E[m][pu][4b] * Mo[m][pu][8d] ----
#pragma unroll
    for (int m = 0; m < 8; ++m) {
      float4 ef = *reinterpret_cast<const float4*>(&E[(m * 16 + pu) * 17 + 4 * bq]);
      float4 v0 = *reinterpret_cast<const float4*>(
          &MoL[(m * 16 + pu) * 32 + (((2 * dh) ^ (pu & 7)) * 4)]);
      float4 v1 = *reinterpret_cast<const float4*>(
          &MoL[(m * 16 + pu) * 32 + (((2 * dh + 1) ^ (pu & 7)) * 4)]);
      float es[4] = {ef.x, ef.y, ef.z, ef.w};
#pragma unroll
      for (int i = 0; i < 4; ++i) {
        acc[i][0].x = fmaf(es[i], v0.x, acc[i][0].x);
        acc[i][0].y = fmaf(es[i], v0.y, acc[i][0].y);
        acc[i][0].z = fmaf(es[i], v0.z, acc[i][0].z);
        acc[i][0].w = fmaf(es[i], v0.w, acc[i][0].w);
        acc[i][1].x = fmaf(es[i], v1.x, acc[i][1].x);
        acc[i][1].y = fmaf(es[i], v1.y, acc[i][1].y);
        acc[i][1].z = fmaf(es[i], v1.z, acc[i][1].z);
        acc[i][1].w = fmaf(es[i], v1.w, acc[i][1].w);
      }
    }
  }

  // epilogue: overwrite stats cells with final outputs
#pragma unroll
  for (int i = 0; i < 4; ++i) {
    float* dst = outs + ((size_t)(b0 + 4 * bq + i) * 512 + u0 + pu) * 32 + 8 * dh;
    *reinterpret_cast<float4*>(dst)     = acc[i][0];
    *reinterpret_cast<float4*>(dst + 4) = acc[i][1];
  }
}

extern "C" void kernel_launch(void* const* d_in, const int* in_sizes, int n_in,
                              void* d_out, int out_size, void* d_ws, size_t ws_size,
                              hipStream_t stream) {
  const float* x    = (const float*)d_in[0];   // [512][4096]
  const float* ma   = (const float*)d_in[1];   // [512][512][32]
  const float* mo   = (const float*)d_in[2];   // [512][512][32]
  const float* rnd  = (const float*)d_in[3];   // [512][512][512]
  const float* w1   = (const float*)d_in[4];   // [8][512][256]
  const float* b1   = (const float*)d_in[5];   // [8][256]
  const float* w2   = (const float*)d_in[6];   // [8][256][2048]
  const float* b2   = (const float*)d_in[7];   // [8][2048]
  const float* temp = (const float*)d_in[8];   // [512]

  float* out  = (float*)d_out;
  float* att  = out;                  // 8388608
  float* ga   = out + 8388608;        // 1048576
  float* wbuf = out + 9437184;        // 134217728
  float* outs = out + 143654912;      // 8388608

  gemm_split<<<dim3(32, 8), 256, 0, stream>>>(x, 4096, 512, w1, 256, b1, ga, 2048);
  gemm_split<<<dim3(256, 8), 256, 0, stream>>>(ga, 2048, 256, w2, 2048, b2, att, 16384);
  scores_mfma_v5<<<dim3(32, 32), 256, 0, stream>>>(att, ma, rnd, temp, wbuf, outs);
  emit_outputs_v3<<<dim3(32, 32), 256, 0, stream>>>(mo, wbuf, outs);
}

// Round 13
// 807.682 us; speedup vs baseline: 1.4774x; 1.0184x over previous
//
#include <hip/hip_runtime.h>
#include <math.h>

#define NEGBIG (-1e30f)
#define GLB_PTR(x) ((const __attribute__((address_space(1))) void*)(x))
#define LDS_PTR(x) ((__attribute__((address_space(3))) void*)(x))

typedef __bf16 bf16x8 __attribute__((ext_vector_type(8)));
typedef float  f32x4  __attribute__((ext_vector_type(4)));

// Sizes: B=512, S=8, U=512, D=32, G=8, DIM_IN=4096, DAG=2048
// out layout: att[512*16384] | ga[512*2048] | w[512^3] | outputs[512*16384]
// No-max softmax: scores kernel stores p = exp(s) (masked -> 0) into the w
// region and accumulates L_g; stats cell (b,u) floats [0..7] = 1/(8 L_g).
// emit kernel: w = p * IL_g + PV accumulation; overwrites stats cells.

// ---------------- K1/K2: per-split fp32 GEMM (64x64 tile, Kstep 16) ----------------
__global__ __launch_bounds__(256) void gemm_split(
    const float* __restrict__ A, int lda, int Ksz,
    const float* __restrict__ Bw, int NS,
    const float* __restrict__ bias,
    float* __restrict__ C, int ldc)
{
  const int n0 = blockIdx.x * 64;
  const int b0 = blockIdx.y * 64;
  const int s  = n0 / NS;
  const float* Bp = Bw + (size_t)s * Ksz * NS;
  const int nloc0 = n0 - s * NS;
  const int acol0 = s * Ksz;

  __shared__ float As[16][64];
  __shared__ float Bs[16][64];

  const int t  = threadIdx.x;
  const int tb = t & 15, tn = t >> 4;
  float acc[4][4] = {};

  for (int k0 = 0; k0 < Ksz; k0 += 16) {
    {
      int r = t & 63, g = t >> 6;
      float4 v = *reinterpret_cast<const float4*>(
          A + (size_t)(b0 + r) * lda + acol0 + k0 + 4 * g);
      As[4*g+0][r] = v.x; As[4*g+1][r] = v.y; As[4*g+2][r] = v.z; As[4*g+3][r] = v.w;
    }
    {
      int kk = t >> 4, n4 = t & 15;
      float4 v = *reinterpret_cast<const float4*>(
          Bp + (size_t)(k0 + kk) * NS + nloc0 + 4 * n4);
      *reinterpret_cast<float4*>(&Bs[kk][4*n4]) = v;
    }
    __syncthreads();
#pragma unroll
    for (int k = 0; k < 16; ++k) {
      float4 a4 = *reinterpret_cast<const float4*>(&As[k][4*tb]);
      float4 b4 = *reinterpret_cast<const float4*>(&Bs[k][4*tn]);
      float av[4] = {a4.x, a4.y, a4.z, a4.w};
      float bv[4] = {b4.x, b4.y, b4.z, b4.w};
#pragma unroll
      for (int i = 0; i < 4; ++i)
#pragma unroll
        for (int j = 0; j < 4; ++j)
          acc[i][j] = fmaf(av[i], bv[j], acc[i][j]);
    }
    __syncthreads();
  }
#pragma unroll
  for (int i = 0; i < 4; ++i) {
    int row = b0 + 4*tb + i;
    int col = n0 + 4*tn;
    float4 o;
    o.x = acc[i][0] + bias[col + 0];
    o.y = acc[i][1] + bias[col + 1];
    o.z = acc[i][2] + bias[col + 2];
    o.w = acc[i][3] + bias[col + 3];
    *reinterpret_cast<float4*>(C + (size_t)row * ldc + col) = o;
  }
}

// ---------------- K3a (MFMA v5): p = exp(masked score) + group sums ----------------
// (unchanged from round 12 -- validated at < 381 us)
__global__ __launch_bounds__(256) void scores_mfma_v5(
    const float* __restrict__ att,   // [512][512][32]
    const float* __restrict__ ma,    // [512][512][32]
    const float* __restrict__ rnd,   // [512][512][512]
    const float* __restrict__ temp,  // [512]
    float* __restrict__ wout,        // [512][512][512] <- p values
    float* __restrict__ stats)       // outs region base
{
  __shared__ float MaL[2048 * 4];    // 32 KB staged ma chunk (f4 slots)
  __shared__ float tr[256 * 17];     // 17 KB C transpose
  const int b0 = blockIdx.x * 16;
  const int u0 = blockIdx.y * 16;
  const int t  = threadIdx.x;
  const int w  = t >> 6, l = t & 63;
  const int lm = l & 15, kb = l >> 4;      // MFMA decode: m / k-block
  const int eu = t & 15, eb = t >> 4;      // emit decode: u / b
  const int gbe = b0 + eb;

  const float tmp = temp[u0 + eu];         // emit's single temperature

  // A-fragments (att) for the wave's 4 u's, split hi/lo bf16, loaded once
  bf16x8 Ahi[4], Alo[4];
#pragma unroll
  for (int q = 0; q < 4; ++q) {
    const float* ap = att + (size_t)(b0 + lm) * 16384
                    + (size_t)(u0 + 4 * w + q) * 32 + kb * 8;
    float4 a0 = *reinterpret_cast<const float4*>(ap);
    float4 a1 = *reinterpret_cast<const float4*>(ap + 4);
    float af[8] = {a0.x, a0.y, a0.z, a0.w, a1.x, a1.y, a1.z, a1.w};
#pragma unroll
    for (int j = 0; j < 8; ++j) {
      __bf16 h = (__bf16)af[j];
      Ahi[q][j] = h;
      Alo[q][j] = (__bf16)(af[j] - (float)h);
    }
  }

  // staging source offsets: slot s = k*256 + t holds ma(m=s>>7, u=(s>>3)&15,
  // d-quad = (s&7) ^ (m&7)) of the current chunk
  int off[8];
#pragma unroll
  for (int k = 0; k < 8; ++k) {
    int s = k * 256 + t;
    int mm = s >> 7, uu = (s >> 3) & 15, d4s = s & 7;
    off[k] = mm * 16384 + (u0 + uu) * 32 + ((d4s ^ (mm & 7)) << 2);
  }

  float Ls[8];
#pragma unroll
  for (int g = 0; g < 8; ++g) Ls[g] = 0.f;

  const float* rbase = rnd  + (size_t)gbe * 262144 + u0 + eu;   // + m*512
  float*       wbase = wout + (size_t)gbe * 262144 + u0 + eu;

  // prologue: stage chunk 0 + rnd chunk 0
#pragma unroll
  for (int k = 0; k < 8; ++k)
    __builtin_amdgcn_global_load_lds(GLB_PTR(ma + (size_t)off[k]),
                                     LDS_PTR(&MaL[(k * 256 + w * 64) * 4]), 16, 0, 0);
  float rc[16], rn[16];
#pragma unroll
  for (int j = 0; j < 16; ++j) rc[j] = rbase[(size_t)j * 512];

#pragma unroll 1
  for (int c = 0; c < 32; ++c) {
    const int m0 = c * 16;
    __syncthreads();                 // A: MaL(c) drained; tr(c-1) consumed

    // ---- MFMA role: 4 u's of this wave ----
#pragma unroll
    for (int q = 0; q < 4; ++q) {
      const int uq = 4 * w + q;
      const int s0 = (lm << 7) + (uq << 3) + ((2 * kb)     ^ (lm & 7));
      const int s1 = (lm << 7) + (uq << 3) + ((2 * kb + 1) ^ (lm & 7));
      float4 g0 = *reinterpret_cast<const float4*>(&MaL[s0 * 4]);
      float4 g1 = *reinterpret_cast<const float4*>(&MaL[s1 * 4]);
      float bf[8] = {g0.x, g0.y, g0.z, g0.w, g1.x, g1.y, g1.z, g1.w};
      bf16x8 Bhi, Blo;
#pragma unroll
      for (int j = 0; j < 8; ++j) {
        __bf16 h = (__bf16)bf[j];
        Bhi[j] = h;
        Blo[j] = (__bf16)(bf[j] - (float)h);
      }
      f32x4 a = {0.f, 0.f, 0.f, 0.f};
      a = __builtin_amdgcn_mfma_f32_16x16x32_bf16(Ahi[q], Blo, a, 0, 0, 0);
      a = __builtin_amdgcn_mfma_f32_16x16x32_bf16(Alo[q], Bhi, a, 0, 0, 0);
      a = __builtin_amdgcn_mfma_f32_16x16x32_bf16(Ahi[q], Bhi, a, 0, 0, 0);
      // C: b = kb*4+i, m = lm  ->  row = b*16 + m, swizzled u slot
#pragma unroll
      for (int i = 0; i < 4; ++i) {
        const int row = (kb * 4 + i) * 16 + lm;
        tr[row * 17 + (uq ^ ((row >> 6) << 2))] = a[i];
      }
    }
    __syncthreads();                 // B: tr(c) visible; MaL(c) reads done

    // ---- issue chunk c+1 staging + rnd(c+1): covered by emit(c) ----
    if (c < 31) {
#pragma unroll
      for (int k = 0; k < 8; ++k)
        __builtin_amdgcn_global_load_lds(
            GLB_PTR(ma + (size_t)off[k] + (size_t)(m0 + 16) * 16384),
            LDS_PTR(&MaL[(k * 256 + w * 64) * 4]), 16, 0, 0);
#pragma unroll
      for (int j = 0; j < 16; ++j)
        rn[j] = rbase[(size_t)(m0 + 16 + j) * 512];
    }

    // ---- emit role: thread (u = eu, b = eb), 16 m, coalesced IO ----
    const int swz = (eb >> 2) << 2;  // (row>>6) for row = eb*16 + m
    const float* trow = &tr[(eb * 16) * 17 + (eu ^ swz)];
#pragma unroll
    for (int j = 0; j < 16; ++j) {
      const int gm = m0 + j;
      float p;
      if ((rc[j] < 0.1f) | (gm == gbe)) p = 0.f;
      else                              p = __expf(trow[j * 17] * tmp);
      wbase[(size_t)gm * 512] = p;
      Ls[j & 7] += p;
    }
#pragma unroll
    for (int j = 0; j < 16; ++j) rc[j] = rn[j];
  }

  // ---- stats: thread owns (b,u) completely -- direct write, no merge ----
  {
    float* cell = stats + ((size_t)gbe * 512 + u0 + eu) * 32;
#pragma unroll
    for (int g = 0; g < 8; ++g) cell[g] = 1.0f / (8.0f * Ls[g]);
  }
}

// ---------------- K3b v4: w = p*IL + outputs, u-fastest phase A keying ----------
// Block 16b x 16u, 64 chunks of 8 m. Phase A thread = (eu = t&15, gg = t>>4):
// m = gg&7 (static -> group g = m), b = (gg>>3) + 2k for k = 0..7. Every w
// read/write instruction touches 4 dense 64-B lines (16 consecutive u x 4
// (m,b) cells) -- the r12 scores fix applied to emit. IL[8] loaded once.
// E layout [(m*16+u)*17 + b] and phase B are unchanged from v3.
__global__ __launch_bounds__(256) void emit_outputs_v4(
    const float* __restrict__ mo,    // [512][512][32]
    float* __restrict__ w,           // in: p values, out: final w
    float* __restrict__ outs)        // in: stats cells (IL), out: outputs
{
  __shared__ float MoL[8 * 16 * 32];
  __shared__ float E[8 * 16 * 17];
  const int u0 = blockIdx.x * 16;
  const int b0 = blockIdx.y * 16;
  const int t  = threadIdx.x;
  // phase A ids: u-fastest
  const int eu = t & 15, gg = t >> 4;
  const int ma_ = gg & 7, bpar = gg >> 3;          // m (== group), b parity
  // phase B ids (unchanged)
  const int pu = t >> 4, bq = (t >> 2) & 3, dh = t & 3;

  // IL for the 8 owned b's at fixed (u = eu, g = ma_)
  float Sreg[8];
#pragma unroll
  for (int k = 0; k < 8; ++k)
    Sreg[k] = outs[((size_t)(b0 + bpar + 2 * k) * 512 + u0 + eu) * 32 + ma_];

  float4 acc[4][2];
#pragma unroll
  for (int i = 0; i < 4; ++i) {
    acc[i][0] = make_float4(0.f, 0.f, 0.f, 0.f);
    acc[i][1] = make_float4(0.f, 0.f, 0.f, 0.f);
  }

  // w cell pointers: wcell_k = w[b0+bpar+2k][m = mc+ma_][u0+eu]
  float* wb = w + (size_t)(b0 + bpar) * 262144 + (size_t)ma_ * 512 + u0 + eu;
  // per-k stride: 2*262144; per-chunk stride: 8*512

  const float* msrc0;  const float* msrc1;  const float* msrc2;  const float* msrc3;
  int loff0, loff1, loff2, loff3;
  {
    int P, mm, uu, dq;
    P = t;          mm = P >> 7; uu = (P >> 3) & 15; dq = P & 7;
    msrc0 = mo + (size_t)mm * 16384 + (size_t)(u0 + uu) * 32 + (dq ^ (uu & 7)) * 4;
    loff0 = P * 4;
    P = 256 + t;    mm = P >> 7; uu = (P >> 3) & 15; dq = P & 7;
    msrc1 = mo + (size_t)mm * 16384 + (size_t)(u0 + uu) * 32 + (dq ^ (uu & 7)) * 4;
    loff1 = P * 4;
    P = 512 + t;    mm = P >> 7; uu = (P >> 3) & 15; dq = P & 7;
    msrc2 = mo + (size_t)mm * 16384 + (size_t)(u0 + uu) * 32 + (dq ^ (uu & 7)) * 4;
    loff2 = P * 4;
    P = 768 + t;    mm = P >> 7; uu = (P >> 3) & 15; dq = P & 7;
    msrc3 = mo + (size_t)mm * 16384 + (size_t)(u0 + uu) * 32 + (dq ^ (uu & 7)) * 4;
    loff3 = P * 4;
  }

  // prologue: chunk 0 into regs
  float wpre[8];
  float4 smo0, smo1, smo2, smo3;
  {
#pragma unroll
    for (int k = 0; k < 8; ++k)
      wpre[k] = wb[(size_t)(2 * k) * 262144];
    smo0 = *reinterpret_cast<const float4*>(msrc0);
    smo1 = *reinterpret_cast<const float4*>(msrc1);
    smo2 = *reinterpret_cast<const float4*>(msrc2);
    smo3 = *reinterpret_cast<const float4*>(msrc3);
  }

#pragma unroll 1
  for (int c = 0; c < 64; ++c) {
    const int mc = c * 8;
    if (c) __syncthreads();            // phase B of c-1 done with E/MoL

    // ---- phase A: v = p*IL -> w writeback + E; ds_write staged mo ----
    {
      float* wp = wb + (size_t)mc * 512;
#pragma unroll
      for (int k = 0; k < 8; ++k) {
        float v = wpre[k] * Sreg[k];
        wp[(size_t)(2 * k) * 262144] = v;
        E[(ma_ * 16 + eu) * 17 + bpar + 2 * k] = v;
      }
    }
    *reinterpret_cast<float4*>(&MoL[loff0]) = smo0;
    *reinterpret_cast<float4*>(&MoL[loff1]) = smo1;
    *reinterpret_cast<float4*>(&MoL[loff2]) = smo2;
    *reinterpret_cast<float4*>(&MoL[loff3]) = smo3;
    __syncthreads();                   // E + MoL ready

    // ---- issue prefetch for chunk c+1 ----
    if (c < 63) {
      const float* wp = wb + (size_t)(mc + 8) * 512;
#pragma unroll
      for (int k = 0; k < 8; ++k)
        wpre[k] = wp[(size_t)(2 * k) * 262144];
      const size_t moff = (size_t)(mc + 8) * 16384;
      smo0 = *reinterpret_cast<const float4*>(msrc0 + moff);
      smo1 = *reinterpret_cast<const float4*>(msrc1 + moff);
      smo2 = *reinterpret_cast<const float4*>(msrc2 + moff);
      smo3 = *reinterpret_cast<const float4*>(msrc3 + moff);
    }

    // ---- phase B: acc[4b][8d] += E[m][pu][4b] * Mo[m][pu][8d] ----
#pragma unroll
    for (int m = 0; m < 8; ++m) {
      float4 ef = *reinterpret_cast<const float4*>(&E[(m * 16 + pu) * 17 + 4 * bq]);
      float4 v0 = *reinterpret_cast<const float4*>(
          &MoL[(m * 16 + pu) * 32 + (((2 * dh) ^ (pu & 7)) * 4)]);
      float4 v1 = *reinterpret_cast<const float4*>(
          &MoL[(m * 16 + pu) * 32 + (((2 * dh + 1) ^ (pu & 7)) * 4)]);
      float es[4] = {ef.x, ef.y, ef.z, ef.w};
#pragma unroll
      for (int i = 0; i < 4; ++i) {
        acc[i][0].x = fmaf(es[i], v0.x, acc[i][0].x);
        acc[i][0].y = fmaf(es[i], v0.y, acc[i][0].y);
        acc[i][0].z = fmaf(es[i], v0.z, acc[i][0].z);
        acc[i][0].w = fmaf(es[i], v0.w, acc[i][0].w);
        acc[i][1].x = fmaf(es[i], v1.x, acc[i][1].x);
        acc[i][1].y = fmaf(es[i], v1.y, acc[i][1].y);
        acc[i][1].z = fmaf(es[i], v1.z, acc[i][1].z);
        acc[i][1].w = fmaf(es[i], v1.w, acc[i][1].w);
      }
    }
  }

  // epilogue: overwrite stats cells with final outputs
#pragma unroll
  for (int i = 0; i < 4; ++i) {
    float* dst = outs + ((size_t)(b0 + 4 * bq + i) * 512 + u0 + pu) * 32 + 8 * dh;
    *reinterpret_cast<float4*>(dst)     = acc[i][0];
    *reinterpret_cast<float4*>(dst + 4) = acc[i][1];
  }
}

extern "C" void kernel_launch(void* const* d_in, const int* in_sizes, int n_in,
                              void* d_out, int out_size, void* d_ws, size_t ws_size,
                              hipStream_t stream) {
  const float* x    = (const float*)d_in[0];   // [512][4096]
  const float* ma   = (const float*)d_in[1];   // [512][512][32]
  const float* mo   = (const float*)d_in[2];   // [512][512][32]
  const float* rnd  = (const float*)d_in[3];   // [512][512][512]
  const float* w1   = (const float*)d_in[4];   // [8][512][256]
  const float* b1   = (const float*)d_in[5];   // [8][256]
  const float* w2   = (const float*)d_in[6];   // [8][256][2048]
  const float* b2   = (const float*)d_in[7];   // [8][2048]
  const float* temp = (const float*)d_in[8];   // [512]

  float* out  = (float*)d_out;
  float* att  = out;                  // 8388608
  float* ga   = out + 8388608;        // 1048576
  float* wbuf = out + 9437184;        // 134217728
  float* outs = out + 143654912;      // 8388608

  gemm_split<<<dim3(32, 8), 256, 0, stream>>>(x, 4096, 512, w1, 256, b1, ga, 2048);
  gemm_split<<<dim3(256, 8), 256, 0, stream>>>(ga, 2048, 256, w2, 2048, b2, att, 16384);
  scores_mfma_v5<<<dim3(32, 32), 256, 0, stream>>>(att, ma, rnd, temp, wbuf, outs);
  emit_outputs_v4<<<dim3(32, 32), 256, 0, stream>>>(mo, wbuf, outs);
}